// Round 5
// baseline (469.707 us; speedup 1.0000x reference)
//
#include <hip/hip_runtime.h>
#include <hip/hip_fp16.h>

// Problem dims (fixed): B=64, N=T=64, L=128, H=256, V=256, G=3H=768
typedef _Float16 f16;
typedef _Float16 f16x2 __attribute__((ext_vector_type(2)));
typedef _Float16 f16x4 __attribute__((ext_vector_type(4)));
typedef _Float16 f16x8 __attribute__((ext_vector_type(8)));
typedef float f32x4 __attribute__((ext_vector_type(4)));
typedef unsigned int u32;

#define DEV static __device__ __forceinline__

DEV float dot2f(u32 a, u32 b, float c) {
#if __has_builtin(__builtin_amdgcn_fdot2)
    return __builtin_amdgcn_fdot2(__builtin_bit_cast(f16x2, a),
                                  __builtin_bit_cast(f16x2, b), c, false);
#else
    f16x2 x = __builtin_bit_cast(f16x2, a), y = __builtin_bit_cast(f16x2, b);
    return c + (float)x[0] * (float)y[0] + (float)x[1] * (float)y[1];
#endif
}

DEV float rcp_fast(float x) {
#if __has_builtin(__builtin_amdgcn_rcpf)
    return __builtin_amdgcn_rcpf(x);
#else
    return 1.f / x;
#endif
}
DEV float sigmoid_f(float x) { return rcp_fast(1.f + __expf(-x)); }
DEV float tanh_f(float x)    { return 1.f - 2.f * rcp_fast(1.f + __expf(2.f * x)); }

DEV u32 addrelu2(u32 a, u32 b) {
    f16x2 x = __builtin_bit_cast(f16x2, a) + __builtin_bit_cast(f16x2, b);
    f16x2 z = {};
    x = __builtin_elementwise_max(x, z);
    return __builtin_bit_cast(u32, x);
}

// ---------------- workspace layout (bytes) ----------------
#define WS_AWHH  0u          // 2 layers * 24576 uint4 (Whh A-fragments, f16)
#define WS_WIH1  786432u     // 196608 f16
#define WS_NHW1  1179648u    // 65536 f16
#define WS_NHW2  1310720u
#define WS_SHW1  1441792u    // 32768 f16
#define WS_SHW2  1507328u    // 128 f16
#define WS_EHW2  1507584u    // 256 f16
#define WS_WKC   1508096u    // 65536 f16
#define WS_WQC   1639168u
#define WS_BKC   1770240u    // 256 f32
#define WS_BQC   1771264u
#define WS_H0    1772288u    // 64*256 f32
#define WS_GXT0  1837824u    // 256*768 f16 token gate table
#define WS_H1    2231040u    // 4096*256 f16 rows (t*64+b); overlaid by HID later
#define WS_HID   2231040u    // 4096*256 f16 rows (b*64+t)
#define WS_GX1R  4328192u    // 4096*768 f16 rows (t*64+b)
#define WS_GXS   10619648u   // gx slabs: 64t*4wg*8w*3gi*64lane uint4 = 6291456 B
#define WS_HK    10619648u   // overlay (after GRUs done)
#define WS_HQ    12716800u

// ---------------- fp32 -> fp16 weight conversion ----------------
struct ConvArgs { const float* src[8]; f16* dst[8]; int cnt[8]; };

__global__ void k_convert(ConvArgs a) {
    int idx = blockIdx.x * 256 + threadIdx.x;
#pragma unroll
    for (int s = 0; s < 8; s++) {
        if (idx < a.cnt[s]) { a.dst[s][idx] = (f16)a.src[s][idx]; return; }
        idx -= a.cnt[s];
    }
}

// ---------------- Whh -> MFMA A-fragment staging ----------------
// awhh[layer][ ((w*6+tl)*8+kk)*64 + lane ] = 8 f16: Whh[row][k0..k0+7]
// row = gi*256 + w*32 + p*16 + (lane&15), k0 = kk*32 + (lane>>4)*8, tl = gi*2+p
__global__ __launch_bounds__(256) void k_wstage(const float* whh0, const float* whh1,
                                                uint4* awhh) {
    int idx = blockIdx.x * 256 + threadIdx.x;   // 2*8*6*8*64 = 49152 total
    int lane = idx & 63; int x = idx >> 6;
    int kk = x & 7; x >>= 3;
    int tl = x % 6; x /= 6;
    int w = x & 7; int layer = x >> 3;
    if (layer > 1) return;
    int gi = tl >> 1, p = tl & 1;
    int row = gi * 256 + w * 32 + p * 16 + (lane & 15);
    int k0 = kk * 32 + (lane >> 4) * 8;
    const float* src = (layer ? whh1 : whh0) + row * 256 + k0;
    float4 aa = *(const float4*)src, bb = *(const float4*)(src + 4);
    f16x8 v;
    v[0]=(f16)aa.x; v[1]=(f16)aa.y; v[2]=(f16)aa.z; v[3]=(f16)aa.w;
    v[4]=(f16)bb.x; v[5]=(f16)bb.y; v[6]=(f16)bb.z; v[7]=(f16)bb.w;
    awhh[layer * 24576 + ((w * 6 + tl) * 8 + kk) * 64 + lane] = __builtin_bit_cast(uint4, v);
}

// ---------------- gxt0 table: emb @ Wih0.T + bih0 (+bhh0 for r,z) ----------------
__global__ __launch_bounds__(256) void k_gxt0(const float* emb, const float* wih0,
                                              const float* bih0, const float* bhh0,
                                              f16* gxt0) {
    int v0 = blockIdx.x * 8, tid = threadIdx.x;
    __shared__ float es[8][256];
    for (int i = tid; i < 2048; i += 256) es[i >> 8][i & 255] = emb[v0 * 256 + i];
    __syncthreads();
#pragma unroll 1
    for (int pp = 0; pp < 3; pp++) {
        int g = tid + pp * 256;
        float bias = bih0[g] + (g < 512 ? bhh0[g] : 0.f);
        const float4* wrow = (const float4*)(wih0 + g * 256);
        float acc[8];
#pragma unroll
        for (int r = 0; r < 8; r++) acc[r] = bias;
#pragma unroll 1
        for (int k = 0; k < 64; k++) {
            float4 wv = wrow[k];
#pragma unroll
            for (int r = 0; r < 8; r++)
                acc[r] += es[r][4*k]*wv.x + es[r][4*k+1]*wv.y + es[r][4*k+2]*wv.z + es[r][4*k+3]*wv.w;
        }
        for (int r = 0; r < 8; r++) gxt0[(v0 + r) * 768 + g] = (f16)acc[r];
    }
}

// ---------------- h0 = relu(z@W1.T+b1)@W2.T+b2 ----------------
__global__ __launch_bounds__(256) void k_h0(const float* z, const float* w1, const float* b1,
                                            const float* w2, const float* b2, float* h0) {
    int b = blockIdx.x, tid = threadIdx.x;
    __shared__ float zs[128];
    __shared__ float t1[256];
    if (tid < 128) zs[tid] = z[b * 128 + tid];
    __syncthreads();
    const float4* w = (const float4*)(w1 + tid * 128);
    float acc = b1[tid];
    for (int k = 0; k < 32; k++) {
        float4 wv = w[k];
        acc += zs[4*k]*wv.x + zs[4*k+1]*wv.y + zs[4*k+2]*wv.z + zs[4*k+3]*wv.w;
    }
    t1[tid] = fmaxf(acc, 0.f);
    __syncthreads();
    const float4* ww = (const float4*)(w2 + tid * 256);
    float a2 = b2[tid];
    for (int k = 0; k < 64; k++) {
        float4 wv = ww[k];
        a2 += t1[4*k]*wv.x + t1[4*k+1]*wv.y + t1[4*k+2]*wv.z + t1[4*k+3]*wv.w;
    }
    h0[b * 256 + tid] = a2;
}

// ---------------- combined edge weights ----------------
__global__ __launch_bounds__(256) void k_wkq(const float* ehW1, const float* ekW, const float* eqW,
                                             const float* ekb, const float* eqb, const float* ehb1,
                                             f16* wkc, f16* wqc, float* bkc, float* bqc) {
    int wgi = blockIdx.x;
    int which = wgi & 1, o0 = (wgi >> 1) * 8, tid = threadIdx.x;
    __shared__ float w1s[8][256];
    for (int i = tid; i < 2048; i += 256)
        w1s[i >> 8][i & 255] = ehW1[(o0 + (i >> 8)) * 512 + (which ? 256 : 0) + (i & 255)];
    __syncthreads();
    const float* m = which ? eqW : ekW;
    float acc[8] = {0,0,0,0,0,0,0,0};
#pragma unroll 1
    for (int mm = 0; mm < 256; mm++) {
        float mv = m[mm * 256 + tid];
#pragma unroll
        for (int r = 0; r < 8; r++) acc[r] += w1s[r][mm] * mv;
    }
    f16* outw = which ? wqc : wkc;
    for (int r = 0; r < 8; r++) outw[(o0 + r) * 256 + tid] = (f16)acc[r];
    const float* bb = which ? eqb : ekb;
    __shared__ float red[256];
#pragma unroll 1
    for (int r = 0; r < 8; r++) {
        red[tid] = w1s[r][tid] * bb[tid];
        __syncthreads();
        for (int s = 128; s > 0; s >>= 1) {
            if (tid < s) red[tid] += red[tid + s];
            __syncthreads();
        }
        if (tid == 0)
            (which ? bqc : bkc)[o0 + r] = red[0] + (which ? 0.f : ehb1[o0 + r]);
        __syncthreads();
    }
}

// ---------------- gx slab builder: per-lane MFMA-update-layout gx fragments --------
// gxs[ (((t*4+wg)*8+w)*3 + gi)*64 + lane ] = 8 f16 = gx[gate gi][g = w*32+p*16+rg*4+reg][b=wg*16+n]
// for p in {0,1}, reg in {0..3}; lane = rg*16+n.  Layer0: src row = token gate-table row.
__global__ __launch_bounds__(512) void k_slab(const f16* srcrows, const int* toks,
                                              uint4* gxs, int layer) {
    int t = blockIdx.x >> 2, wg = blockIdx.x & 3;
    int tid = threadIdx.x, w = tid >> 6, lane = tid & 63;
    int n = lane & 15, rg = lane >> 4;
    int b = wg * 16 + n;
    int srow;
    if (layer == 0) srow = (t == 0) ? 2 : toks[b * 64 + t - 1];
    else            srow = t * 64 + b;
    const f16* sp = srcrows + srow * 768;
    uint4* dst = gxs + (((t * 4 + wg) * 8 + w) * 3) * 64 + lane;
#pragma unroll
    for (int gi = 0; gi < 3; gi++) {
        uint2 lo = *(const uint2*)(sp + gi * 256 + w * 32 + rg * 4);
        uint2 hi = *(const uint2*)(sp + gi * 256 + w * 32 + 16 + rg * 4);
        uint4 o; o.x = lo.x; o.y = lo.y; o.z = hi.x; o.w = hi.y;
        dst[gi * 64] = o;
    }
}

// ---------------- MFMA GRU: 4 WGs x 16 batch, Whh in registers ----------------
// Wave w owns gate rows gi*256 + [32w, 32w+32) for gi=0..2 (6 M-tiles of 16x16x32).
// h double-buffered in LDS, K-MAJOR layout: 16B slot (c,n) at byte c*256 + n*16,
// c = k/8 chunk (32 chunks), n = batch (16). Wave reads are contiguous 1KB -> conflict-free.
__global__ __launch_bounds__(512, 2) void k_gru_mfma(
    const uint4* awhh, const uint4* gxs, const float* bhh,
    const float* h0, f16* hout, int layer) {
    int wg = blockIdx.x;
    int tid = threadIdx.x;
    int w = tid >> 6, lane = tid & 63;
    int n = lane & 15, rg = lane >> 4;
    int b0 = wg * 16;
    int e0 = 32 * w + rg * 4;

    // Whh A-fragments (static, 192 VGPR)
    f16x8 wa[6][8];
    {
        const uint4* src = awhh + (w * 48) * 64 + lane;
#pragma unroll
        for (int tl = 0; tl < 6; tl++)
#pragma unroll
            for (int kk = 0; kk < 8; kk++)
                wa[tl][kk] = __builtin_bit_cast(f16x8, src[(tl * 8 + kk) * 64]);
    }
    // bhh_n for this lane's 8 rows (f16 to save regs)
    f16x8 bn;
    {
        const float4* p0 = (const float4*)(bhh + 512 + e0);
        float4 v0 = p0[0], v1 = p0[4];
        bn[0]=(f16)v0.x; bn[1]=(f16)v0.y; bn[2]=(f16)v0.z; bn[3]=(f16)v0.w;
        bn[4]=(f16)v1.x; bn[5]=(f16)v1.y; bn[6]=(f16)v1.z; bn[7]=(f16)v1.w;
    }
    float hold[8];
    {
        const float4* p0 = (const float4*)(h0 + (b0 + n) * 256 + e0);
        float4 v0 = p0[0], v1 = p0[4];
        hold[0]=v0.x; hold[1]=v0.y; hold[2]=v0.z; hold[3]=v0.w;
        hold[4]=v1.x; hold[5]=v1.y; hold[6]=v1.z; hold[7]=v1.w;
    }

    __shared__ __align__(16) unsigned char hbuf[2][8192];
    {
        int n2 = tid >> 5, kq = tid & 31;   // kq = k-chunk (8 f16), n2 = batch
        const float4* s = (const float4*)(h0 + (b0 + n2) * 256 + kq * 8);
        float4 a = s[0], bq = s[1];
        f16x8 hv;
        hv[0]=(f16)a.x; hv[1]=(f16)a.y; hv[2]=(f16)a.z; hv[3]=(f16)a.w;
        hv[4]=(f16)bq.x; hv[5]=(f16)bq.y; hv[6]=(f16)bq.z; hv[7]=(f16)bq.w;
        *(uint4*)&hbuf[0][kq * 256 + n2 * 16] = __builtin_bit_cast(uint4, hv);
    }
    __syncthreads();

    int roff = rg * 256 + n * 16;                         // + kk*1024 per k-step
    int wbase = (4 * w + (rg >> 1)) * 256 + n * 16 + (rg & 1) * 8;
    const uint4* gxp = gxs + ((wg * 8 + w) * 3) * 64 + lane;
    int cur = 0;

    for (int t = 0; t < 64; t++) {
        uint4 g0 = gxp[0], g1 = gxp[64], g2 = gxp[128];
        gxp += 6144;
        f32x4 acc[6];
#pragma unroll
        for (int tl = 0; tl < 6; tl++) acc[tl] = (f32x4){0.f, 0.f, 0.f, 0.f};
        const unsigned char* hb = &hbuf[cur][0];
        uint4 bc = *(const uint4*)&hb[roff];
#pragma unroll
        for (int kk = 0; kk < 8; kk++) {
            uint4 bnx = bc;
            if (kk < 7) bnx = *(const uint4*)&hb[roff + (kk + 1) * 1024];
            f16x8 bfr = __builtin_bit_cast(f16x8, bc);
#pragma unroll
            for (int tl = 0; tl < 6; tl++)
                acc[tl] = __builtin_amdgcn_mfma_f32_16x16x32_f16(wa[tl][kk], bfr, acc[tl], 0, 0, 0);
            bc = bnx;
        }
        // in-register gate update
        f16x8 gr = __builtin_bit_cast(f16x8, g0);
        f16x8 gz = __builtin_bit_cast(f16x8, g1);
        f16x8 gn = __builtin_bit_cast(f16x8, g2);
        f16x4 h40, h41;
#pragma unroll
        for (int p = 0; p < 2; p++)
#pragma unroll
            for (int reg = 0; reg < 4; reg++) {
                int q = p * 4 + reg;
                float r  = sigmoid_f((float)gr[q] + acc[0 + p][reg]);
                float zg = sigmoid_f((float)gz[q] + acc[2 + p][reg]);
                float nn = tanh_f((float)gn[q] + r * (acc[4 + p][reg] + (float)bn[q]));
                float h = (1.f - zg) * nn + zg * hold[q];
                hold[q] = h;
                if (p == 0) h40[reg] = (f16)h; else h41[reg] = (f16)h;
            }
        // p=0 rows: k = e0..e0+3 -> chunk 4w+(rg>>1), 8B offset (rg&1)*8
        // p=1 rows: k = e0+16..e0+19 -> chunk +2
        *(f16x4*)&hbuf[cur ^ 1][wbase] = h40;
        *(f16x4*)&hbuf[cur ^ 1][wbase + 512] = h41;
        int row = (layer == 0) ? (t * 64 + b0 + n) : ((b0 + n) * 64 + t);
        *(f16x4*)&hout[row * 256 + e0] = h40;
        *(f16x4*)&hout[row * 256 + e0 + 16] = h41;
        __syncthreads();
        cur ^= 1;
    }
}

// ---------------- shared GEMM helper (pipelined, no spill) ------------
template <int R>
DEV void lgemm(const u32 h[][128], const u32* wrow, float bias, float* acc) {
    const uint4* wc = (const uint4*)wrow;
#pragma unroll
    for (int r = 0; r < R; r++) acc[r] = bias;
    uint4 w0 = wc[0], w1 = wc[1], w2 = wc[2], w3 = wc[3];
#pragma unroll 1
    for (int c = 0; c < 8; c++) {
        int cn = (c + 1) & 7;
        uint4 n0 = wc[4*cn], n1 = wc[4*cn+1], n2 = wc[4*cn+2], n3 = wc[4*cn+3];
#pragma unroll
        for (int r = 0; r < R; r++) {
            const uint4* hp = (const uint4*)&h[r][c * 16];
            uint4 h0 = hp[0], h1 = hp[1], h2 = hp[2], h3 = hp[3];
            float a = acc[r];
            a = dot2f(w0.x, h0.x, a); a = dot2f(w0.y, h0.y, a);
            a = dot2f(w0.z, h0.z, a); a = dot2f(w0.w, h0.w, a);
            a = dot2f(w1.x, h1.x, a); a = dot2f(w1.y, h1.y, a);
            a = dot2f(w1.z, h1.z, a); a = dot2f(w1.w, h1.w, a);
            a = dot2f(w2.x, h2.x, a); a = dot2f(w2.y, h2.y, a);
            a = dot2f(w2.z, h2.z, a); a = dot2f(w2.w, h2.w, a);
            a = dot2f(w3.x, h3.x, a); a = dot2f(w3.y, h3.y, a);
            a = dot2f(w3.z, h3.z, a); a = dot2f(w3.w, h3.w, a);
            acc[r] = a;
        }
        w0 = n0; w1 = n1; w2 = n2; w3 = n3;
    }
}

// ---------------- gx1 = h1 @ Wih1.T + biases (rows t*64+b) ----------------
__global__ __launch_bounds__(256) void k_gx1(const f16* h1, const u32* wih1,
                                             const float* bih1, const float* bhh1, f16* gx1) {
    int rb = blockIdx.x, row0 = rb * 8, tid = threadIdx.x;
    __shared__ __align__(16) u32 hs[8][128];
    const u32* src = (const u32*)h1 + row0 * 128;
    for (int i = tid; i < 1024; i += 256) hs[i >> 7][i & 127] = src[i];
    __syncthreads();
#pragma unroll 1
    for (int pp = 0; pp < 3; pp++) {
        int g = tid + pp * 256;
        float bias = bih1[g] + (g < 512 ? bhh1[g] : 0.f);
        float acc[8];
        lgemm<8>(hs, wih1 + g * 128, bias, acc);
#pragma unroll
        for (int r = 0; r < 8; r++) gx1[(row0 + r) * 768 + g] = (f16)acc[r];
    }
}

// ---------------- node + stop heads ----------------
__global__ __launch_bounds__(256) void k_node_stop(const f16* hid,
        const u32* nhw1, const float* nhb1, const u32* nhw2, const float* nhb2,
        const u32* shw1, const float* shb1, const u32* shw2, const float* shb2,
        float* outn, float* outs) {
    int rb = blockIdx.x, row0 = rb * 16, tid = threadIdx.x;
    __shared__ __align__(16) u32 hs[16][128];
    __shared__ __align__(16) u32 t1[16][128];
    const u32* src = (const u32*)hid + row0 * 128;
    for (int i = tid; i < 2048; i += 256) hs[i >> 7][i & 127] = src[i];
    __syncthreads();
    float acc[16];
    lgemm<16>(hs, nhw1 + tid * 128, nhb1[tid], acc);
#pragma unroll
    for (int r = 0; r < 16; r++) ((f16*)t1[r])[tid] = (f16)fmaxf(acc[r], 0.f);
    __syncthreads();
    lgemm<16>(t1, nhw2 + tid * 128, nhb2[tid], acc);
#pragma unroll
    for (int r = 0; r < 16; r++) outn[(row0 + r) * 256 + tid] = acc[r];
    __shared__ __align__(16) u32 s1[16][64];
    if (tid < 128) {
        float a[16];
        lgemm<16>(hs, shw1 + tid * 128, shb1[tid], a);
#pragma unroll
        for (int r = 0; r < 16; r++) ((f16*)s1[r])[tid] = (f16)fmaxf(a[r], 0.f);
    }
    __syncthreads();
    if (tid < 16) {
        float a = shb2[0];
#pragma unroll
        for (int k = 0; k < 64; k++) a = dot2f(shw2[k], s1[tid][k], a);
        outs[row0 + tid] = a;
    }
}

// ---------------- hk/hq with combined weights ----------------
__global__ __launch_bounds__(256) void k_kq(const f16* hid, const u32* wkc, const u32* wqc,
                                            const float* bkc, const float* bqc,
                                            f16* hk, f16* hq) {
    int rb = blockIdx.x, row0 = rb * 16, tid = threadIdx.x;
    __shared__ __align__(16) u32 hs[16][128];
    const u32* src = (const u32*)hid + row0 * 128;
    for (int i = tid; i < 2048; i += 256) hs[i >> 7][i & 127] = src[i];
    __syncthreads();
    float acc[16];
    lgemm<16>(hs, wkc + tid * 128, bkc[tid], acc);
#pragma unroll
    for (int r = 0; r < 16; r++) hk[(row0 + r) * 256 + tid] = (f16)acc[r];
    float acc2[16];
    lgemm<16>(hs, wqc + tid * 128, bqc[tid], acc2);
#pragma unroll
    for (int r = 0; r < 16; r++) hq[(row0 + r) * 256 + tid] = (f16)acc2[r];
}

// ---------------- edge logits ----------------
__global__ __launch_bounds__(256) void k_edge(const f16* hk, const f16* hq, const u32* w2,
                                              const float* ehb2, const int* mask,
                                              float* oute) {
    int bidx = blockIdx.x, b = bidx >> 2, itile = (bidx & 3) * 16, tid = threadIdx.x;
    __shared__ __align__(16) u32 hqs[64][128];
    __shared__ __align__(16) u32 hks[16][128];
    __shared__ __align__(16) u32 w2s[128];
    for (int i = tid; i < 8192; i += 256) {
        int row = i >> 7, dw = i & 127;
        u32 v = ((const u32*)hq)[(b * 64 + row) * 128 + dw];
        int slot = (dw >> 2) ^ (row & 31);
        hqs[row][(slot << 2) | (dw & 3)] = v;
    }
    for (int i = tid; i < 2048; i += 256) {
        int row = i >> 7, dw = i & 127;
        hks[row][dw] = ((const u32*)hk)[(b * 64 + itile + row) * 128 + dw];
    }
    if (tid < 128) w2s[tid] = w2[tid];
    __syncthreads();

    int wv = tid >> 6, j = tid & 63;
    bool mj = mask[b * 64 + j] != 0;
    float b2 = ehb2[0];
#pragma unroll 1
    for (int il = 0; il < 4; il++) {
        int ir = wv * 4 + il, i = itile + ir;
        bool mi = mask[b * 64 + i] != 0;
        float acc = 0.f;
#pragma unroll
        for (int s = 0; s < 32; s++) {
            uint4 a = *(const uint4*)&hks[ir][s << 2];
            uint4 q = *(const uint4*)&hqs[j][(s ^ (j & 31)) << 2];
            uint4 ww = *(const uint4*)&w2s[s << 2];
            acc = dot2f(addrelu2(a.x, q.x), ww.x, acc);
            acc = dot2f(addrelu2(a.y, q.y), ww.y, acc);
            acc = dot2f(addrelu2(a.z, q.z), ww.z, acc);
            acc = dot2f(addrelu2(a.w, q.w), ww.w, acc);
        }
        float out = acc + b2;
        if (!(mi && mj)) out = -INFINITY;
        oute[(b * 64 + i) * 64 + j] = out;
    }
}

// ---------------- host ----------------
extern "C" void kernel_launch(void* const* d_in, const int* in_sizes, int n_in,
                              void* d_out, int out_size, void* d_ws, size_t ws_size,
                              hipStream_t stream) {
    (void)in_sizes; (void)n_in; (void)out_size; (void)ws_size;
    const float* z      = (const float*)d_in[0];
    const int*   toks   = (const int*)d_in[1];
    const int*   mask   = (const int*)d_in[2];
    const float* l2hW1 = (const float*)d_in[3];
    const float* l2hb1 = (const float*)d_in[4];
    const float* l2hW2 = (const float*)d_in[5];
    const float* l2hb2 = (const float*)d_in[6];
    const float* emb   = (const float*)d_in[7];
    const float* wih0  = (const float*)d_in[8];
    const float* whh0  = (const float*)d_in[9];
    const float* bih0  = (const float*)d_in[10];
    const float* bhh0  = (const float*)d_in[11];
    const float* wih1  = (const float*)d_in[12];
    const float* whh1  = (const float*)d_in[13];
    const float* bih1  = (const float*)d_in[14];
    const float* bhh1  = (const float*)d_in[15];
    const float* nhW1  = (const float*)d_in[16];
    const float* nhb1  = (const float*)d_in[17];
    const float* nhW2  = (const float*)d_in[18];
    const float* nhb2  = (const float*)d_in[19];
    const float* ekW   = (const float*)d_in[20];
    const float* ekb   = (const float*)d_in[21];
    const float* eqW   = (const float*)d_in[22];
    const float* eqb   = (const float*)d_in[23];
    const float* ehW1  = (const float*)d_in[24];
    const float* ehb1  = (const float*)d_in[25];
    const float* ehW2  = (const float*)d_in[26];
    const float* ehb2  = (const float*)d_in[27];
    const float* shW1  = (const float*)d_in[28];
    const float* shb1  = (const float*)d_in[29];
    const float* shW2  = (const float*)d_in[30];
    const float* shb2  = (const float*)d_in[31];

    char* ws = (char*)d_ws;
    uint4* awhh = (uint4*)(ws + WS_AWHH);
    f16* wih1h = (f16*)(ws + WS_WIH1);
    f16* nhw1h = (f16*)(ws + WS_NHW1);
    f16* nhw2h = (f16*)(ws + WS_NHW2);
    f16* shw1h = (f16*)(ws + WS_SHW1);
    f16* shw2h = (f16*)(ws + WS_SHW2);
    f16* ehw2h = (f16*)(ws + WS_EHW2);
    f16* wkc   = (f16*)(ws + WS_WKC);
    f16* wqc   = (f16*)(ws + WS_WQC);
    float* bkc = (float*)(ws + WS_BKC);
    float* bqc = (float*)(ws + WS_BQC);
    float* h0w = (float*)(ws + WS_H0);
    f16* gxt0  = (f16*)(ws + WS_GXT0);
    f16* h1w   = (f16*)(ws + WS_H1);
    f16* hidw  = (f16*)(ws + WS_HID);
    f16* gx1r  = (f16*)(ws + WS_GX1R);
    uint4* gxs = (uint4*)(ws + WS_GXS);
    f16* hkw   = (f16*)(ws + WS_HK);
    f16* hqw   = (f16*)(ws + WS_HQ);

    float* outn = (float*)d_out;
    float* oute = (float*)d_out + 1048576;
    float* outs = (float*)d_out + 1310720;

    ConvArgs ca;
    ca.src[0] = wih1; ca.dst[0] = wih1h; ca.cnt[0] = 196608;
    ca.src[1] = nhW1; ca.dst[1] = nhw1h; ca.cnt[1] = 65536;
    ca.src[2] = nhW2; ca.dst[2] = nhw2h; ca.cnt[2] = 65536;
    ca.src[3] = shW1; ca.dst[3] = shw1h; ca.cnt[3] = 32768;
    ca.src[4] = shW2; ca.dst[4] = shw2h; ca.cnt[4] = 128;
    ca.src[5] = ehW2; ca.dst[5] = ehw2h; ca.cnt[5] = 256;
    ca.src[6] = nullptr; ca.dst[6] = nullptr; ca.cnt[6] = 0;
    ca.src[7] = nullptr; ca.dst[7] = nullptr; ca.cnt[7] = 0;

    k_convert<<<1410, 256, 0, stream>>>(ca);
    k_wstage<<<192, 256, 0, stream>>>(whh0, whh1, awhh);
    k_gxt0<<<32, 256, 0, stream>>>(emb, wih0, bih0, bhh0, gxt0);
    k_h0<<<64, 256, 0, stream>>>(z, l2hW1, l2hb1, l2hW2, l2hb2, h0w);
    k_wkq<<<64, 256, 0, stream>>>(ehW1, ekW, eqW, ekb, eqb, ehb1, wkc, wqc, bkc, bqc);
    k_slab<<<256, 512, 0, stream>>>(gxt0, toks, gxs, 0);
    k_gru_mfma<<<4, 512, 0, stream>>>(awhh, gxs, bhh0, h0w, h1w, 0);
    k_gx1<<<512, 256, 0, stream>>>(h1w, (const u32*)wih1h, bih1, bhh1, gx1r);
    k_slab<<<256, 512, 0, stream>>>(gx1r, toks, gxs, 1);
    k_gru_mfma<<<4, 512, 0, stream>>>(awhh + 24576, gxs, bhh1, h0w, hidw, 1);
    k_node_stop<<<256, 256, 0, stream>>>(hidw, (const u32*)nhw1h, nhb1, (const u32*)nhw2h, nhb2,
                                         (const u32*)shw1h, shb1, (const u32*)shw2h, shb2,
                                         outn, outs);
    k_kq<<<256, 256, 0, stream>>>(hidw, (const u32*)wkc, (const u32*)wqc, bkc, bqc, hkw, hqw);
    k_edge<<<256, 256, 0, stream>>>(hkw, hqw, (const u32*)ehw2h, ehb2, mask, oute);
}